// Round 2
// baseline (236.535 us; speedup 1.0000x reference)
//
#include <hip/hip_runtime.h>
#include <cstdint>
#include <cstddef>

// v: (B=16, L=16384, D=128) fp32.
// out[b, 2j+e, d] = (e==0 ? min : max)(v[b, p, d], v[b, p+1, d]),
//   p = (2j - s_d) mod L,  s_d = (d==0 ? 0 : 2d-2)  (always even).
#define L_DIM 16384
#define D_DIM 128
#define B_DIM 16

#define TR 256           // output rows per block
#define DG 16            // columns per block -> shift span 30, halo 32
#define HALO 32
#define ROWS (TR + HALO) // 288 input rows staged
#define NCHUNK (ROWS / 16)  // 18 load chunks (16 rows x 64B each)

__global__ __launch_bounds__(256, 8) void butterfly_cmpex_kernel(
    const float* __restrict__ v, float* __restrict__ out) {
  __shared__ float lds[ROWS * DG];  // 18 KB -> 8 blocks/CU (32 waves/CU)

  // XCD-chunked swizzle: grid.x = 64 = 8 XCD x 8; linear id % 8 == rt_raw % 8,
  // so XCD k gets contiguous rtiles [8k, 8k+8) -> shared halos stay in its L2.
  const int rt_raw = blockIdx.x;
  const int rtile  = (rt_raw & 7) * 8 + (rt_raw >> 3);
  const int g      = blockIdx.y;   // 0..7 column group
  const int b      = blockIdx.z;
  const int r0     = rtile * TR;
  const int d0     = g * DG;
  const int smax   = 32 * g + 28;  // max shift in this column group
  const int rin0   = r0 - smax;    // first staged input row (may be < 0)

  const int t    = threadIdx.x;
  const int lane = t & 63;
  const int wave = t >> 6;

  const float* vb = v + (size_t)b * (L_DIM * D_DIM);

  // ---- Load: ROWS x 16 floats -> LDS via global_load_lds (16B/lane) ----
  // One chunk = 16 rows x 64B = 1KB per wave-instr; LDS dest linear.
  const int lrow  = lane >> 2;  // 0..15
  const int lcol4 = lane & 3;   // 0..3
  for (int chunk = wave; chunk < NCHUNK; chunk += 4) {
    const int grow = (rin0 + chunk * 16 + lrow) & (L_DIM - 1);
    const float* gp = vb + (size_t)grow * D_DIM + d0 + lcol4 * 4;
    float* lp = &lds[chunk * 16 * DG];  // wave-uniform LDS base
    __builtin_amdgcn_global_load_lds(
        (const __attribute__((address_space(1))) uint32_t*)gp,
        (__attribute__((address_space(3))) uint32_t*)lp,
        16 /*bytes per lane*/, 0 /*offset*/, 0 /*aux*/);
  }
  __syncthreads();  // drains vmcnt for global_load_lds

  // ---- Compute: diagonal pair gather from LDS, min/max, coalesced store ----
  const int c  = t & 15;   // column within group
  const int jg = t >> 4;   // 0..15 pair-row subgroup
  const int d  = d0 + c;
  const int s  = (d == 0) ? 0 : (2 * d - 2);
  const int roff = smax - s;  // 0..28; lds_row = 2*j_local + roff < ROWS

  float* outb = out + (size_t)b * (L_DIM * D_DIM);

#pragma unroll
  for (int k = 0; k < TR / 32; ++k) {  // 8 iterations
    const int j_local = k * 16 + jg;
    const int lr = 2 * j_local + roff;
    const float a0 = lds[lr * DG + c];
    const float a1 = lds[(lr + 1) * DG + c];
    const float lo = fminf(a0, a1);
    const float hi = fmaxf(a0, a1);
    const size_t o = (size_t)(r0 + 2 * j_local) * D_DIM + d;
    outb[o]         = lo;  // 16 lanes cover one 64B line
    outb[o + D_DIM] = hi;
  }
}

extern "C" void kernel_launch(void* const* d_in, const int* in_sizes, int n_in,
                              void* d_out, int out_size, void* d_ws, size_t ws_size,
                              hipStream_t stream) {
  const float* v = (const float*)d_in[0];
  float* out = (float*)d_out;
  dim3 grid(L_DIM / TR, D_DIM / DG, B_DIM);  // (64, 8, 16)
  dim3 block(256);
  butterfly_cmpex_kernel<<<grid, block, 0, stream>>>(v, out);
}